// Round 4
// baseline (79.478 us; speedup 1.0000x reference)
//
#include <hip/hip_runtime.h>
#include <math.h>

#define N_LOC 16384
#define W 128
#define B_SZ 64
#define D_CTRL 1024
#define TOTAL_OUT 390   // 3*W + 6

__device__ __forceinline__ float dot4(float4 a, float4 b) {
    return a.x * b.x + a.y * b.y + a.z * b.z + a.w * b.w;
}

__device__ __forceinline__ float softplus_f(float x) {
    return fmaxf(x, 0.0f) + log1pf(expf(-fabsf(x)));
}

__device__ __forceinline__ float wave_reduce_sum(float v) {
#pragma unroll
    for (int off = 32; off >= 1; off >>= 1) v += __shfl_xor(v, off);
    return v;
}

// ---------------------------------------------------------------------------
// K1: raw[b][o] = cs[b] . fc_w[o] + fc_b[o]
// grid (13 o-chunks, 8 b-tiles), block 256. 8 cs rows staged in LDS.
// ---------------------------------------------------------------------------
__global__ __launch_bounds__(256) void k1_fc(const float* __restrict__ cs,
                                             const float* __restrict__ fcw,
                                             const float* __restrict__ fcb,
                                             float* __restrict__ raw) {
    __shared__ float4 cs4[8][256];
    const int t = threadIdx.x;
    const int oc = blockIdx.x;      // 0..12, 30 outputs each
    const int btile = blockIdx.y;   // 0..7, 8 b each

    const float4* csg = reinterpret_cast<const float4*>(cs);
#pragma unroll
    for (int i = 0; i < 8; i++) {
        int f4 = t + 256 * i;
        int row = f4 >> 8;
        int col = f4 & 255;
        cs4[row][col] = csg[(btile * 8 + row) * 256 + col];
    }
    __syncthreads();

    const int lane = t & 63;
    const int wv = t >> 6;
    const float4* fcw4 = reinterpret_cast<const float4*>(fcw);

    for (int ol = wv; ol < 30; ol += 4) {
        const int o = oc * 30 + ol;
        float4 r0 = fcw4[o * 256 + 0 * 64 + lane];
        float4 r1 = fcw4[o * 256 + 1 * 64 + lane];
        float4 r2 = fcw4[o * 256 + 2 * 64 + lane];
        float4 r3 = fcw4[o * 256 + 3 * 64 + lane];
#pragma unroll
        for (int b = 0; b < 8; b++) {
            float acc = dot4(cs4[b][0 * 64 + lane], r0);
            acc += dot4(cs4[b][1 * 64 + lane], r1);
            acc += dot4(cs4[b][2 * 64 + lane], r2);
            acc += dot4(cs4[b][3 * 64 + lane], r3);
            acc = wave_reduce_sum(acc);
            if (lane == 0) {
                raw[(btile * 8 + b) * TOTAL_OUT + o] = acc + fcb[o];
            }
        }
    }
}

// ---------------------------------------------------------------------------
// K1b: activations. grid 64 (one per b), block 128.
// keyb = beta * key / max(||key||, 1e-12); also emits beta (score upper bound)
// ---------------------------------------------------------------------------
__global__ __launch_bounds__(128) void k1b_act(const float* __restrict__ raw,
                                               float* __restrict__ keyb,
                                               float* __restrict__ erase,
                                               float* __restrict__ addv,
                                               float* __restrict__ gate,
                                               float* __restrict__ shift,
                                               float* __restrict__ gamma,
                                               float* __restrict__ beta_out) {
    const int b = blockIdx.x;
    const int k = threadIdx.x;
    const float* rb = raw + b * TOTAL_OUT;
    __shared__ float red[2];

    float key = rb[k];
    float ss = wave_reduce_sum(key * key);
    if ((k & 63) == 0) red[k >> 6] = ss;
    __syncthreads();
    float tot = red[0] + red[1];
    float inv = 1.0f / fmaxf(sqrtf(tot), 1e-12f);
    float beta = softplus_f(rb[W]);

    keyb[b * W + k] = beta * key * inv;
    erase[b * W + k] = 1.0f / (1.0f + expf(-rb[W + 6 + k]));
    addv[b * W + k] = tanhf(rb[2 * W + 6 + k]);

    if (k == 0) {
        gate[b] = 1.0f / (1.0f + expf(-rb[W + 1]));
        gamma[b] = softplus_f(rb[W + 5]) + 1.0f;
        beta_out[b] = beta;
        float s0 = rb[W + 2], s1 = rb[W + 3], s2 = rb[W + 4];
        float m = fmaxf(s0, fmaxf(s1, s2));
        float e0 = expf(s0 - m), e1 = expf(s1 - m), e2 = expf(s2 - m);
        float si = 1.0f / (e0 + e1 + e2);
        shift[b * 3 + 0] = e0 * si;
        shift[b * 3 + 1] = e1 * si;
        shift[b * 3 + 2] = e2 * si;
    }
}

// ---------------------------------------------------------------------------
// K3: e[b][n] = exp(keyb[b].mem[n]/max(||mem[n]||,eps) - beta[b])
//     + per-(b, 32n-tile) partial sums partialS[b][512]
// grid 512 (32 n each), block 256 = 32 n-lanes x 8 b-groups (8 b each).
// keyb broadcast from LDS (conflict-free); mem rows from global (L1 reuse).
// ---------------------------------------------------------------------------
__global__ __launch_bounds__(256) void k3_scores(const float* __restrict__ mem,
                                                 const float* __restrict__ keyb,
                                                 const float* __restrict__ beta_,
                                                 float* __restrict__ e_buf,
                                                 float* __restrict__ partialS) {
    __shared__ float4 kb4[B_SZ][32];   // 32 KB
    const int t = threadIdx.x;

    const float4* kg = reinterpret_cast<const float4*>(keyb);
    float4* kbp = reinterpret_cast<float4*>(kb4);
#pragma unroll
    for (int i = 0; i < 8; i++) kbp[t + 256 * i] = kg[t + 256 * i];
    __syncthreads();

    const int nl = t & 31;
    const int n = blockIdx.x * 32 + nl;
    const int bg = t >> 5;             // 0..7 -> b = bg*8 + bi
    const float4* mrow = reinterpret_cast<const float4*>(mem) + (size_t)n * 32;

    float acc[8];
#pragma unroll
    for (int i = 0; i < 8; i++) acc[i] = 0.0f;
    float nrm = 0.0f;

#pragma unroll 8
    for (int k4 = 0; k4 < 32; k4++) {
        float4 mv = mrow[k4];
        nrm += dot4(mv, mv);
#pragma unroll
        for (int bi = 0; bi < 8; bi++) {
            acc[bi] += dot4(kb4[bg * 8 + bi][k4], mv);
        }
    }

    const float r = 1.0f / fmaxf(sqrtf(nrm), 1e-12f);
    float ev[8];
#pragma unroll
    for (int bi = 0; bi < 8; bi++) {
        const int b = bg * 8 + bi;
        float e = __expf(acc[bi] * r - beta_[b]);
        ev[bi] = e;
        e_buf[(size_t)b * N_LOC + n] = e;
    }
    // half-wave (32-lane) reduction: offsets < 32 stay within each half
#pragma unroll
    for (int bi = 0; bi < 8; bi++) {
        float v = ev[bi];
#pragma unroll
        for (int off = 16; off >= 1; off >>= 1) v += __shfl_xor(v, off);
        ev[bi] = v;
    }
    if (nl == 0) {
#pragma unroll
        for (int bi = 0; bi < 8; bi++) {
            partialS[(bg * 8 + bi) * 512 + blockIdx.x] = ev[bi];
        }
    }
}

// ---------------------------------------------------------------------------
// K4a: per (b, 1024-chunk): S = sum(partialS[b][:]) (fixed order);
//      w_g = (gate/S)*e + (1-gate)*wprev; circular 3-tap shift (halo via
//      2 extra scalar loads each side); p = clip^gamma; partialP[b][16].
// grid 1024 = 64 b x 16 chunks, block 256, 4 elems/thread.
// ---------------------------------------------------------------------------
__global__ __launch_bounds__(256) void k4a_shift(const float* __restrict__ e_buf,
                                                 const float* __restrict__ wprev,
                                                 const float* __restrict__ partialS,
                                                 const float* __restrict__ gate_,
                                                 const float* __restrict__ shift_,
                                                 const float* __restrict__ gamma_,
                                                 float* __restrict__ p_buf,
                                                 float* __restrict__ partialP) {
    __shared__ float r4[4];
    const int blk = blockIdx.x;
    const int b = blk >> 4;
    const int c = blk & 15;
    const int t = threadIdx.x;

    const float* erow = e_buf + (size_t)b * N_LOC;
    const float* wrow = wprev + (size_t)b * N_LOC;

    // S reduce: 512 partials, fixed-order tree -> deterministic
    const float* ps = partialS + b * 512;
    float sv = ps[t] + ps[t + 256];
    sv = wave_reduce_sum(sv);
    if ((t & 63) == 0) r4[t >> 6] = sv;
    __syncthreads();
    const float S = r4[0] + r4[1] + r4[2] + r4[3];

    const float gate = gate_[b];
    const float ga = gate / S;
    const float og = 1.0f - gate;
    const float gm = gamma_[b];
    const float sh0 = shift_[b * 3 + 0];
    const float sh1 = shift_[b * 3 + 1];
    const float sh2 = shift_[b * 3 + 2];

    const int nb = c * 1024 + 4 * t;
    float4 e4 = *reinterpret_cast<const float4*>(erow + nb);
    float4 w4 = *reinterpret_cast<const float4*>(wrow + nb);
    const int nm1 = (nb + N_LOC - 1) & (N_LOC - 1);
    const int np4 = (nb + 4) & (N_LOC - 1);
    float em1 = erow[nm1], wm1 = wrow[nm1];
    float ep4 = erow[np4], wp4s = wrow[np4];

    float g_m1 = ga * em1 + og * wm1;
    float g0 = ga * e4.x + og * w4.x;
    float g1 = ga * e4.y + og * w4.y;
    float g2 = ga * e4.z + og * w4.z;
    float g3 = ga * e4.w + og * w4.w;
    float g_p4 = ga * ep4 + og * wp4s;

    float s0_ = sh0 * g_m1 + sh1 * g0 + sh2 * g1;
    float s1_ = sh0 * g0 + sh1 * g1 + sh2 * g2;
    float s2_ = sh0 * g1 + sh1 * g2 + sh2 * g3;
    float s3_ = sh0 * g2 + sh1 * g3 + sh2 * g_p4;

    float4 pv;
    pv.x = exp2f(gm * __log2f(fmaxf(s0_, 1e-9f)));
    pv.y = exp2f(gm * __log2f(fmaxf(s1_, 1e-9f)));
    pv.z = exp2f(gm * __log2f(fmaxf(s2_, 1e-9f)));
    pv.w = exp2f(gm * __log2f(fmaxf(s3_, 1e-9f)));
    *reinterpret_cast<float4*>(p_buf + (size_t)b * N_LOC + nb) = pv;

    float sp = pv.x + pv.y + pv.z + pv.w;
    sp = wave_reduce_sum(sp);
    __syncthreads();               // r4 reuse safe
    if ((t & 63) == 0) r4[t >> 6] = sp;
    __syncthreads();
    if (t == 0) partialP[b * 16 + c] = r4[0] + r4[1] + r4[2] + r4[3];
}

// ---------------------------------------------------------------------------
// K4c: w_new = p / (S2 + eps), in place. grid 1024, block 256, float4/thread.
// ---------------------------------------------------------------------------
__global__ __launch_bounds__(256) void k4c_norm(const float* __restrict__ partialP,
                                                float* __restrict__ p_buf) {
    const int blk = blockIdx.x;
    const int b = blk >> 4;
    const int c = blk & 15;
    const int t = threadIdx.x;

    const float* pp = partialP + b * 16;
    float s = 0.0f;
#pragma unroll
    for (int j = 0; j < 16; j++) s += pp[j];   // uniform, fixed order
    const float inv = 1.0f / (s + 1e-9f);

    float4* p4 = reinterpret_cast<float4*>(p_buf + (size_t)b * N_LOC + c * 1024);
    float4 v = p4[t];
    v.x *= inv; v.y *= inv; v.z *= inv; v.w *= inv;
    p4[t] = v;
}

// ---------------------------------------------------------------------------
// K5: new_mem[n][w] = mem[n][w]*(1 - em) + am,
//     em/am = (1/64) sum_b wnew[b][n]*{erase,add}[b][w]
// grid 1024 (16 n each), block 256 (128 w x 2 n-halves), 8 n per thread.
// ---------------------------------------------------------------------------
__global__ __launch_bounds__(256) void k5_update(const float* __restrict__ wnew,
                                                 const float* __restrict__ erase,
                                                 const float* __restrict__ addv,
                                                 const float* __restrict__ mem,
                                                 float* __restrict__ outmem) {
    const int t = threadIdx.x;
    const int w = t & 127;
    const int nh = t >> 7;
    const int nb = blockIdx.x * 16 + nh * 8;

    float ae[8], aa[8];
#pragma unroll
    for (int i = 0; i < 8; i++) { ae[i] = 0.0f; aa[i] = 0.0f; }

    for (int b = 0; b < B_SZ; b++) {
        float we = erase[b * W + w];
        float wa = addv[b * W + w];
        const float* wr = wnew + (size_t)b * N_LOC + nb;   // wave-uniform
#pragma unroll
        for (int i = 0; i < 8; i++) {
            float wv = wr[i];
            ae[i] += wv * we;
            aa[i] += wv * wa;
        }
    }

    const float inv_b = 1.0f / 64.0f;
#pragma unroll
    for (int i = 0; i < 8; i++) {
        int n = nb + i;
        float em = ae[i] * inv_b;
        float am = aa[i] * inv_b;
        float mv = mem[n * W + w];
        outmem[n * W + w] = mv * (1.0f - em) + am;
    }
}

// ---------------------------------------------------------------------------
extern "C" void kernel_launch(void* const* d_in, const int* in_sizes, int n_in,
                              void* d_out, int out_size, void* d_ws, size_t ws_size,
                              hipStream_t stream) {
    const float* cs    = (const float*)d_in[0];   // (64, 1024)
    const float* mem   = (const float*)d_in[1];   // (16384, 128)
    const float* wprev = (const float*)d_in[2];   // (64, 16384)
    const float* fcw   = (const float*)d_in[3];   // (390, 1024)
    const float* fcb   = (const float*)d_in[4];   // (390,)

    float* out = (float*)d_out;
    float* wnew_out = out;                               // (64, 16384) = p_buf
    float* mem_out = out + (size_t)B_SZ * N_LOC;         // (16384, 128)
    // e lives in the new_memory region (first 1M floats) until K5 overwrites
    // it; p lives in the w_new region and is normalized in place by K4c.
    float* e_buf = mem_out;

    float* wsf = (float*)d_ws;
    float* raw   = wsf;              // 24960
    float* keyb  = raw + 24960;      // 8192
    float* erase = keyb + 8192;      // 8192
    float* addv  = erase + 8192;     // 8192
    float* gate  = addv + 8192;      // 64
    float* shift = gate + 64;        // 192
    float* gamma = shift + 192;      // 64
    float* beta  = gamma + 64;       // 64
    float* partialS = beta + 64;     // 64*512 = 32768 (offset 49984)
    float* partialP = partialS + 32768;  // 64*16 = 1024

    k1_fc<<<dim3(13, 8), 256, 0, stream>>>(cs, fcw, fcb, raw);
    k1b_act<<<64, 128, 0, stream>>>(raw, keyb, erase, addv, gate, shift, gamma, beta);
    k3_scores<<<512, 256, 0, stream>>>(mem, keyb, beta, e_buf, partialS);
    k4a_shift<<<1024, 256, 0, stream>>>(e_buf, wprev, partialS, gate, shift, gamma,
                                        wnew_out, partialP);
    k4c_norm<<<1024, 256, 0, stream>>>(partialP, wnew_out);
    k5_update<<<1024, 256, 0, stream>>>(wnew_out, erase, addv, mem, mem_out);
}